// Round 2
// baseline (30162.619 us; speedup 1.0000x reference)
//
#include <hip/hip_runtime.h>

// Problem constants (B=32, C=128, H=72, W=200, K=9, PAD=4)
#define CC  128
#define HH  72
#define WW  200
#define HW_ (HH*WW)        // 14400
#define CHW (CC*HW_)       // 1843200
#define W12_FLOATS (CC*CC*12)    // 196608 floats per tensor

// Persistent-path scratch lives in device globals (ws only holds the
// transposed state): 4 repacked weight tensors + per-b sync counters.
__device__ float g_w12[4][W12_FLOATS];
__device__ int   g_ctr[2][32 * 32];     // [kernel][b*32], padded 128B/b

// ---------------------------------------------------------------------------
// Repack w[c][ci][9] -> w12[(c*128+ci)*12 + k] (16B-aligned rows, zero pad).
// Same (c,ci) access pattern as the original, so the sweep body only changes
// stride 9 -> 12. Block (0,0) also zeroes the sync counters.
// Grid (64, 4), block 256; blockIdx.y selects tensor {d,u,r,l}.
// ---------------------------------------------------------------------------
__global__ __launch_bounds__(256) void repack_zero_kern(
    const float* __restrict__ w0, const float* __restrict__ w1,
    const float* __restrict__ w2, const float* __restrict__ w3)
{
    if (blockIdx.x == 0 && blockIdx.y == 0) {
        for (int i = threadIdx.x; i < 2 * 32 * 32; i += 256)
            ((int*)g_ctr)[i] = 0;
    }
    const float* src = (blockIdx.y == 0) ? w0 : (blockIdx.y == 1) ? w1
                     : (blockIdx.y == 2) ? w2 : w3;
    float* dst = g_w12[blockIdx.y];
    int idx = blockIdx.x * 256 + threadIdx.x;   // 16384 = (c, ci)
    const float* wp = src + (size_t)idx * 9;
    float* op = dst + (size_t)idx * 12;
    #pragma unroll
    for (int k = 0; k < 9; k++) op[k] = wp[k];
    op[9] = op[10] = op[11] = 0.f;
}

// ---------------------------------------------------------------------------
// Persistent sweep pair (fwd then bwd) over rows R of a (B, C, R, L) state,
// L contiguous. One launch does ALL steps of both sweeps.
//   st[b][c][r_dst][l] += relu(bias[c] + sum_{ci,k} w[c][ci][k]*st[b][ci][r_src][l+k-4])
// Block = (ltile, ctile, b). Per-b distributed barrier via cumulative counter:
// a block may compute step s only when ctr[b] >= BPB*(s-1), which provably
// implies EVERY same-b block completed step s-1 (no skew; disjoint writes).
// Release/acquire at agent scope handles cross-XCD visibility.
// Mapping (proven round-0 codegen): NG=TL/LPT l-groups, cgrp=t/NG -> CPT c.
// ---------------------------------------------------------------------------
template<int L, int R, int TL, int CT, int CPT, int LPT, int BPB, int CIDX>
__global__ __launch_bounds__(256) void sweep_pair_kern(
    float* st, const float* __restrict__ w12f, const float* __restrict__ bf,
    const float* __restrict__ w12b, const float* __restrict__ bbi)
{
    constexpr int WIN = TL + 8;
    constexpr int NG  = TL / LPT;           // = 8 for both instantiations
    __shared__ float lds[CC * WIN];
    const int b     = blockIdx.z;
    const int lbase = blockIdx.x * TL;
    const int cbase = blockIdx.y * CT;
    const int t     = threadIdx.x;
    const int lgrp  = t & (NG - 1);
    const int cgrp  = t / NG;
    const int l0g   = lgrp * LPT;
    const int c0    = cbase + cgrp * CPT;
    int* myctr = &g_ctr[CIDX][b * 32];

    float* stb = st + (size_t)b * CHW;

    for (int ph = 0; ph < 2; ph++) {
        const float* w12  = ph ? w12b : w12f;
        const float* bias = ph ? bbi  : bf;
        const int tbase   = ph ? BPB * (R - 1) : 0;
        for (int s = 1; s <= R - 1; s++) {
            const int r_dst  = ph ? (R - 1 - s) : s;
            const int r_src  = ph ? (R - s)     : (s - 1);
            const int target = tbase + BPB * (s - 1);
            if (target > 0 && t == 0) {
                while (__hip_atomic_load(myctr, __ATOMIC_ACQUIRE,
                                         __HIP_MEMORY_SCOPE_AGENT) < target)
                    __builtin_amdgcn_s_sleep(2);
            }
            __syncthreads();

            // stage prev row window [lbase-4, lbase+TL+4) for all 128 ci
            const float* src = stb + (size_t)r_src * L;
            for (int i = t; i < CC * WIN; i += 256) {
                int ci = i / WIN;
                int lo = i - ci * WIN;
                int l  = lbase - 4 + lo;
                lds[i] = (l >= 0 && l < L) ? src[(size_t)ci * (R * L) + l] : 0.f;
            }
            __syncthreads();

            float acc[CPT][LPT] = {};
            for (int ci = 0; ci < CC; ci++) {
                float p[LPT + 8];
                const float* lp = &lds[ci * WIN + l0g];
                #pragma unroll
                for (int j = 0; j < LPT + 8; j++) p[j] = lp[j];
                #pragma unroll
                for (int c = 0; c < CPT; c++) {
                    const float* wp = w12 + ((size_t)(c0 + c) * CC + ci) * 12;
                    #pragma unroll
                    for (int k = 0; k < 9; k++) {
                        const float wv = wp[k];
                        #pragma unroll
                        for (int j = 0; j < LPT; j++)
                            acc[c][j] = fmaf(wv, p[j + k], acc[c][j]);
                    }
                }
            }

            const int l0 = lbase + l0g;
            if (l0 < L) {                       // tail tile guard (L%LPT==0)
                #pragma unroll
                for (int c = 0; c < CPT; c++) {
                    float* po = stb + (size_t)(c0 + c) * (R * L)
                                    + (size_t)r_dst * L + l0;
                    const float bb2 = bias[c0 + c];
                    #pragma unroll
                    for (int j = 0; j < LPT; j++)
                        po[j] += fmaxf(acc[c][j] + bb2, 0.f);
                }
            }

            __syncthreads();                    // drains vmem before barrier
            if (t == 0)
                __hip_atomic_fetch_add(myctr, 1, __ATOMIC_RELEASE,
                                       __HIP_MEMORY_SCOPE_AGENT);
        }
    }
}

// ---------------------------------------------------------------------------
// Per-plane 2D transpose: in (rows x cols) -> out (cols x rows), z = B*C planes.
// ---------------------------------------------------------------------------
__global__ __launch_bounds__(256) void transpose_kern(
    const float* __restrict__ in, float* __restrict__ outp, int rows, int cols)
{
    __shared__ float tile[32][33];
    const size_t plane = (size_t)rows * cols;
    const float* ip = in   + (size_t)blockIdx.z * plane;
    float*       op = outp + (size_t)blockIdx.z * plane;
    const int c0 = blockIdx.x * 32, r0 = blockIdx.y * 32;
    const int tx = threadIdx.x, ty = threadIdx.y;

    #pragma unroll
    for (int i = 0; i < 32; i += 8) {
        int r = r0 + ty + i, c = c0 + tx;
        if (r < rows && c < cols) tile[ty + i][tx] = ip[(size_t)r * cols + c];
    }
    __syncthreads();
    #pragma unroll
    for (int i = 0; i < 32; i += 8) {
        int r = c0 + ty + i, c = r0 + tx;
        if (r < cols && c < rows) op[(size_t)r * rows + c] = tile[tx][ty + i];
    }
}

// ---------------------------------------------------------------------------
// Launch-per-step fallback kernels (round-0 proven), used only if ws is tiny.
// ---------------------------------------------------------------------------
template<int L>
__global__ __launch_bounds__(256) void step_kern(
    float* __restrict__ st, const float* __restrict__ wgt,
    const float* __restrict__ bias, int r_src, int r_dst)
{
    __shared__ float lds[CC * 40];
    const int b     = blockIdx.z;
    const int lbase = blockIdx.x * 32;
    const int cbase = blockIdx.y * 64;
    const int t     = threadIdx.x;

    const float* src = st + (size_t)b * CHW + (size_t)r_src * L;
    #pragma unroll
    for (int i = 0; i < 20; i++) {
        int idx = t + i * 256;
        int ci  = idx / 40;
        int lo  = idx - ci * 40;
        int l   = lbase - 4 + lo;
        lds[idx] = (l >= 0 && l < L) ? src[(size_t)ci * HW_ + l] : 0.f;
    }
    __syncthreads();

    const int lgrp = t & 7;
    const int cgrp = t >> 3;
    const int l0   = lbase + lgrp * 4;
    const int c0   = cbase + cgrp * 2;

    float acc[2][4] = {};
    for (int ci = 0; ci < CC; ci++) {
        float p[12];
        const float* lp = &lds[ci * 40 + lgrp * 4];
        #pragma unroll
        for (int j = 0; j < 12; j++) p[j] = lp[j];
        #pragma unroll
        for (int c = 0; c < 2; c++) {
            const float* wp = wgt + ((size_t)(c0 + c) * CC + ci) * 9;
            #pragma unroll
            for (int k = 0; k < 9; k++) {
                const float wv = wp[k];
                #pragma unroll
                for (int j = 0; j < 4; j++)
                    acc[c][j] = fmaf(wv, p[j + k], acc[c][j]);
            }
        }
    }

    if (l0 < L) {
        #pragma unroll
        for (int c = 0; c < 2; c++) {
            float* po = st + (size_t)b * CHW + (size_t)(c0 + c) * HW_
                           + (size_t)r_dst * L + l0;
            float4 v = *(float4*)po;
            const float bb = bias[c0 + c];
            v.x += fmaxf(acc[c][0] + bb, 0.f);
            v.y += fmaxf(acc[c][1] + bb, 0.f);
            v.z += fmaxf(acc[c][2] + bb, 0.f);
            v.w += fmaxf(acc[c][3] + bb, 0.f);
            *(float4*)po = v;
        }
    }
}

__global__ __launch_bounds__(256) void stepH_kern(
    float* __restrict__ out, const float* __restrict__ wgt,
    const float* __restrict__ bias, int w_src, int w_dst)
{
    __shared__ float lds[CC * 32];
    const int b     = blockIdx.z;
    const int hbase = blockIdx.x * 24;
    const int cbase = blockIdx.y * 32;
    const int t     = threadIdx.x;

    const float* srcb = out + (size_t)b * CHW + w_src;
    for (int i = t; i < CC * 32; i += 256) {
        int ci = i >> 5;
        int ho = i & 31;
        int h  = hbase - 4 + ho;
        lds[i] = (h >= 0 && h < HH) ? srcb[(size_t)ci * HW_ + (size_t)h * WW] : 0.f;
    }
    __syncthreads();

    const int hgrp  = t & 7;
    const int cgrp  = t >> 3;
    const int h0    = hgrp * 3;
    const int c_out = cbase + cgrp;

    float acc[3] = {};
    for (int ci = 0; ci < CC; ci++) {
        float p[11];
        const float* lp = &lds[ci * 32 + h0];
        #pragma unroll
        for (int j = 0; j < 11; j++) p[j] = lp[j];
        const float* wp = wgt + ((size_t)c_out * CC + ci) * 9;
        #pragma unroll
        for (int k = 0; k < 9; k++) {
            const float wv = wp[k];
            #pragma unroll
            for (int m = 0; m < 3; m++)
                acc[m] = fmaf(wv, p[m + k], acc[m]);
        }
    }

    const float bb = bias[c_out];
    float* po = out + (size_t)b * CHW + (size_t)c_out * HW_
                    + (size_t)(hbase + h0) * WW + w_dst;
    #pragma unroll
    for (int m = 0; m < 3; m++)
        po[(size_t)m * WW] += fmaxf(acc[m] + bb, 0.f);
}

// ---------------------------------------------------------------------------
extern "C" void kernel_launch(void* const* d_in, const int* in_sizes, int n_in,
                              void* d_out, int out_size, void* d_ws, size_t ws_size,
                              hipStream_t stream)
{
    const float* x   = (const float*)d_in[0];
    const float* w_d = (const float*)d_in[1];
    const float* b_d = (const float*)d_in[2];
    const float* w_u = (const float*)d_in[3];
    const float* b_u = (const float*)d_in[4];
    const float* w_r = (const float*)d_in[5];
    const float* b_r = (const float*)d_in[6];
    const float* w_l = (const float*)d_in[7];
    const float* b_l = (const float*)d_in[8];
    float* out = (float*)d_out;
    float* ws  = (float*)d_ws;

    const size_t bytes = (size_t)32 * CHW * sizeof(float);
    hipMemcpyAsync(out, x, bytes, hipMemcpyDeviceToDevice, stream);

    if (ws_size >= bytes) {
        // -------- persistent path: 6 launches total --------
        repack_zero_kern<<<dim3(64, 4), 256, 0, stream>>>(w_d, w_u, w_r, w_l);

        float* q = nullptr;
        hipGetSymbolAddress((void**)&q, HIP_SYMBOL(g_w12));
        const float* q_d = q + 0 * (size_t)W12_FLOATS;
        const float* q_u = q + 1 * (size_t)W12_FLOATS;
        const float* q_r = q + 2 * (size_t)W12_FLOATS;
        const float* q_l = q + 3 * (size_t)W12_FLOATS;

        // D+U: state (B,C,H,W) in out; L=200 contiguous, R=72 rows.
        // 448 blocks (<=2/CU by LDS+VGPR) -> co-resident; 14 blocks per b.
        sweep_pair_kern<WW, HH, 32, 64, 2, 4, 14, 0>
            <<<dim3(7, 2, 32), 256, 0, stream>>>(out, q_d, b_d, q_u, b_u);

        // transpose to (B,C,W,H)
        transpose_kern<<<dim3(7, 3, 4096), dim3(32, 8), 0, stream>>>(out, ws, HH, WW);

        // R+L: L=72 contiguous, R=200 rows. 384 blocks; 12 blocks per b.
        sweep_pair_kern<HH, WW, 24, 32, 1, 3, 12, 1>
            <<<dim3(3, 4, 32), 256, 0, stream>>>(ws, q_r, b_r, q_l, b_l);

        transpose_kern<<<dim3(3, 7, 4096), dim3(32, 8), 0, stream>>>(ws, out, WW, HH);
    } else {
        // -------- last-resort launch-per-step fallback --------
        const dim3 gW(7, 2, 32), blk(256);
        for (int h = 1; h < HH; h++)
            step_kern<WW><<<gW, blk, 0, stream>>>(out, w_d, b_d, h - 1, h);
        for (int h = HH - 2; h >= 0; h--)
            step_kern<WW><<<gW, blk, 0, stream>>>(out, w_u, b_u, h + 1, h);
        const dim3 gB(3, 4, 32);
        for (int w = 1; w < WW; w++)
            stepH_kern<<<gB, blk, 0, stream>>>(out, w_r, b_r, w - 1, w);
        for (int w = WW - 2; w >= 0; w--)
            stepH_kern<<<gB, blk, 0, stream>>>(out, w_l, b_l, w + 1, w);
    }
}